// Round 3
// baseline (5849.956 us; speedup 1.0000x reference)
//
#include <hip/hip_runtime.h>
#include <math.h>

// Problem constants (match reference)
#define NN 200000
#define EE 300000
#define BB 64
#define INV_SQRT_D 0.17677669529663687f

// Workspace layout (floats). Total = N*296 + 3E*4 + ~0.25M ≈ 63.05M floats = 252 MB.
// Round-1 (606 MB) and round-2 (329 MB) both died with GPU memory faults -> assume
// ws budget is ~256MB-class; stay well under.
#define OFF_H    ((size_t)0)                  // [N][128] node features
#define OFF_A    ((size_t)NN * 128)           // [N][128]: phase A = Pq(N*64)+Pk(N*64); phase B = agg
#define OFF_B    ((size_t)NN * 256)           // [N][32]: vt quarter plane
#define OFF_M    ((size_t)NN * 288)           // [N][4] uint-encoded segment max
#define OFF_Z    (OFF_M + (size_t)NN * 4)     // [N][4] softmax denominator
#define OFF_S    (OFF_Z + (size_t)NN * 4)     // [3][E][4] scores -> exp values
#define OFF_WF   (OFF_S + (size_t)3 * EE * 4) // 14 x [128][128] folded weights
#define OFF_BF   (OFF_WF + (size_t)14 * 16384)
#define OFF_POOL (OFF_BF + (size_t)14 * 128)  // [B][256]

__device__ __forceinline__ unsigned enc_f32(float f) {
    unsigned u = __float_as_uint(f);
    return (u & 0x80000000u) ? ~u : (u | 0x80000000u);
}
__device__ __forceinline__ float dec_f32(unsigned u) {
    return (u & 0x80000000u) ? __uint_as_float(u & 0x7FFFFFFFu) : __uint_as_float(~u);
}
__device__ __forceinline__ float gelu_exact(float v) {
    return 0.5f * v * (1.0f + erff(v * 0.70710678118654752f));
}

// ---- fold per-relation head transforms into the projection weights ----
// slot s per layer: 0 = q (plain copy), 1..3 = k@Wk_rel[r], 4..6 = v@Wv_rel[r]
__global__ __launch_bounds__(256) void fold_weights(
    const float* __restrict__ Wkqv, const float* __restrict__ bkqv,
    const float* __restrict__ Wk_rel, const float* __restrict__ Wv_rel,
    float* __restrict__ Wf, float* __restrict__ bf)
{
    __shared__ float Wr[4096];
    const int b = blockIdx.x, t = threadIdx.x;
    const int l = b / 7, s = b % 7;
    const float* Wq = Wkqv + (size_t)l * 49152;   // [128][384]
    if (s == 0) {
        for (int i = t; i < 16384; i += 256) {
            int kk = i >> 7, c = i & 127;
            Wf[(size_t)b * 16384 + i] = Wq[kk * 384 + 128 + c];
        }
        if (t < 128) bf[b * 128 + t] = bkqv[l * 384 + 128 + t];
    } else {
        const int side = (s - 1) / 3, r = (s - 1) % 3;
        const int off = side ? 256 : 0;
        const float* Wrel = (side ? Wv_rel : Wk_rel) + (size_t)(l * 3 + r) * 4096;
        for (int i = t; i < 4096; i += 256) Wr[i] = Wrel[i];
        __syncthreads();
        for (int i = t; i < 16384; i += 256) {
            int kk = i >> 7, c = i & 127, hh = c >> 5, f = c & 31;
            const float* wrow = Wq + kk * 384 + off + hh * 32;
            const float* wr = Wr + hh * 1024 + f;
            float sum = 0.f;
#pragma unroll
            for (int d = 0; d < 32; ++d) sum += wrow[d] * wr[d * 32];
            Wf[(size_t)b * 16384 + i] = sum;
        }
        if (t < 128) {
            int hh = t >> 5, f = t & 31;
            float sum = 0.f;
#pragma unroll
            for (int d = 0; d < 32; ++d)
                sum += bkqv[l * 384 + off + hh * 32 + d] * Wr[hh * 1024 + d * 32 + f];
            bf[b * 128 + t] = sum;
        }
    }
}

// ---------------- input projection: h = [emb[ast], x] @ Win + bin ----------------
__global__ __launch_bounds__(256) void input_proj(
    const float* __restrict__ x, const int* __restrict__ ast,
    const float* __restrict__ emb, const float* __restrict__ Win,
    const float* __restrict__ bin_, float* __restrict__ h)
{
    __shared__ float Ws[69 * 128];
    __shared__ float As[16 * 70];
    const int t = threadIdx.x;
    const int n0 = blockIdx.x * 16;
    for (int i = t; i < 69 * 128; i += 256) Ws[i] = Win[i];
    for (int i = t; i < 16 * 69; i += 256) {
        int nl = i / 69, kk = i - nl * 69;
        int n = n0 + nl;
        float v = (kk < 64) ? emb[ast[n] * 64 + kk] : x[n * 5 + (kk - 64)];
        As[nl * 70 + kk] = v;
    }
    __syncthreads();
    const int c = t & 127;
    const int nh = (t >> 7) * 8;
    float acc[8];
    float bv = bin_[c];
#pragma unroll
    for (int j = 0; j < 8; ++j) acc[j] = bv;
    for (int k = 0; k < 69; ++k) {
        float w = Ws[k * 128 + c];
#pragma unroll
        for (int j = 0; j < 8; ++j) acc[j] += As[(nh + j) * 70 + k] * w;
    }
#pragma unroll
    for (int j = 0; j < 8; ++j) h[(size_t)(n0 + nh + j) * 128 + c] = acc[j];
}

// ---- column-sliced GEMM: out[n][0:CW] = in[n][0:128] @ W[:, c0:c0+CW] + bias[c0:] ----
// out pitch = CW. CW=64 -> 8 rows/thread; CW=32 -> 4 rows/thread. 32 nodes per block.
template<int CW>
__global__ __launch_bounds__(256) void gemm_cw(
    const float* __restrict__ in, const float* __restrict__ W,
    const float* __restrict__ bias, int c0, float* __restrict__ outp)
{
    constexpr int NG = 256 / CW;       // thread groups
    constexpr int NR = 32 / NG;        // rows per thread
    __shared__ float As[32 * 128];     // 16 KB
    __shared__ float Ws[128 * CW];     // 32 KB (CW=64) / 16 KB (CW=32)
    const int t = threadIdx.x;
    const int n0 = blockIdx.x * 32;
    for (int i = t; i < 32 * 32; i += 256) {
        int nl = i >> 5, k4 = i & 31;
        ((float4*)As)[nl * 32 + k4] = *(const float4*)(in + (size_t)(n0 + nl) * 128 + k4 * 4);
    }
    constexpr int C4 = CW / 4;
    for (int i = t; i < 128 * C4; i += 256) {
        int k = i / C4, c4 = i % C4;
        ((float4*)Ws)[i] = *(const float4*)(W + (size_t)k * 128 + c0 + c4 * 4);
    }
    __syncthreads();
    const int c = t % CW;
    const int ng = (t / CW) * NR;
    float acc[NR];
    float bv = bias[c0 + c];
#pragma unroll
    for (int j = 0; j < NR; ++j) acc[j] = bv;
    for (int k = 0; k < 128; ++k) {
        float w = Ws[k * CW + c];
#pragma unroll
        for (int j = 0; j < NR; ++j) acc[j] += As[(ng + j) * 128 + k] * w;
    }
#pragma unroll
    for (int j = 0; j < NR; ++j)
        outp[(size_t)(n0 + ng + j) * CW + c] = acc[j];
}

// ---- edge scores for one head-pair hp: heads 2hp, 2hp+1 ----
__global__ __launch_bounds__(256) void edge_scores_pair(
    const float* __restrict__ q64, const float* __restrict__ k64,
    const int* __restrict__ ei, const float* __restrict__ p2,
    float* __restrict__ s_out, unsigned* __restrict__ m_enc, int hp)
{
    int idx = blockIdx.x * 256 + threadIdx.x;
    if (idx >= EE * 2) return;
    int e = idx >> 1, hh = idx & 1;
    int src = ei[e], dst = ei[EE + e];
    const float4* qp = (const float4*)(q64 + (size_t)dst * 64 + hh * 32);
    const float4* kp = (const float4*)(k64 + (size_t)src * 64 + hh * 32);
    float sum = 0.f;
#pragma unroll
    for (int i = 0; i < 8; ++i) {
        float4 a = qp[i], b = kp[i];
        sum += a.x * b.x + a.y * b.y + a.z * b.z + a.w * b.w;
    }
    float val = sum * p2[hh] * INV_SQRT_D;
    int head = hp * 2 + hh;
    s_out[(size_t)e * 4 + head] = val;
    atomicMax(m_enc + (size_t)dst * 4 + head, enc_f32(val));
}

// ---------------- exp(s - m) and segment sum Z ----------------
__global__ __launch_bounds__(256) void expsum(
    float* __restrict__ s, const unsigned* __restrict__ m_enc, float* __restrict__ z,
    const int* __restrict__ ei0, const int* __restrict__ ei1, const int* __restrict__ ei2)
{
    int idx = blockIdx.x * 256 + threadIdx.x;
    if (idx >= 3 * EE * 4) return;
    int eg = idx >> 2, hh = idx & 3;
    int r = eg / EE;
    int e = eg - r * EE;
    const int* ei = (r == 0) ? ei0 : ((r == 1) ? ei1 : ei2);
    int dst = ei[EE + e];
    float m = dec_f32(m_enc[(size_t)dst * 4 + hh]);
    float ex = expf(s[idx] - m);
    s[idx] = ex;
    atomicAdd(z + (size_t)dst * 4 + hh, ex);
}

// ---- aggregate one head hd: agg[dst][hd*32+c] += (e/(z+eps)) * vt32[src][c] ----
__global__ __launch_bounds__(256) void edge_agg_head(
    const float* __restrict__ vt32, const float* __restrict__ s,
    const float* __restrict__ z, const int* __restrict__ ei,
    float* __restrict__ agg, int hd)
{
    int idx = blockIdx.x * 256 + threadIdx.x;
    if (idx >= EE * 32) return;
    int e = idx >> 5, c = idx & 31;
    int src = ei[e], dst = ei[EE + e];
    float a = s[(size_t)e * 4 + hd] / (z[(size_t)dst * 4 + hd] + 1e-16f);
    atomicAdd(agg + (size_t)dst * 128 + hd * 32 + c, a * vt32[(size_t)src * 32 + c]);
}

// ---------------- out-proj + gelu + skip + LayerNorm (in-place h update) ----------------
__global__ __launch_bounds__(256) void out_ln(
    const float* __restrict__ agg, float* __restrict__ h,
    const float* __restrict__ Wout, const float* __restrict__ bout,
    const float* __restrict__ skipp, const float* __restrict__ lg,
    const float* __restrict__ lb)
{
    __shared__ float As[16 * 128];
    __shared__ float Ws[64 * 128];
    __shared__ float Cs[16 * 128];
    const int t = threadIdx.x;
    const int n0 = blockIdx.x * 16;
    for (int i = t; i < 16 * 32; i += 256) {
        int nl = i >> 5, k4 = i & 31;
        float4 v = *(const float4*)(agg + (size_t)(n0 + nl) * 128 + k4 * 4);
        v.x = gelu_exact(v.x); v.y = gelu_exact(v.y);
        v.z = gelu_exact(v.z); v.w = gelu_exact(v.w);
        ((float4*)As)[nl * 32 + k4] = v;
    }
    const int c = t & 63;
    const int ng = (t >> 6) * 4;
    float acc0[4], acc1[4];
    float b0 = bout[c], b1 = bout[64 + c];
#pragma unroll
    for (int j = 0; j < 4; ++j) { acc0[j] = b0; acc1[j] = b1; }
    for (int kc = 0; kc < 2; ++kc) {
        __syncthreads();
        for (int i = t; i < 64 * 32; i += 256) {
            int k = i >> 5, c4 = i & 31;
            ((float4*)Ws)[i] = *(const float4*)(Wout + (size_t)(kc * 64 + k) * 128 + c4 * 4);
        }
        __syncthreads();
        const float* Ab = As + kc * 64;
        for (int k = 0; k < 64; ++k) {
            float w0 = Ws[k * 128 + c];
            float w1 = Ws[k * 128 + 64 + c];
#pragma unroll
            for (int j = 0; j < 4; ++j) {
                float a = Ab[(ng + j) * 128 + k];
                acc0[j] += a * w0;
                acc1[j] += a * w1;
            }
        }
    }
    float alpha = 1.f / (1.f + expf(-skipp[0]));
    float om = 1.f - alpha;
#pragma unroll
    for (int j = 0; j < 4; ++j) {
        size_t n = (size_t)(n0 + ng + j);
        float o0 = alpha * acc0[j] + om * h[n * 128 + c];
        float o1 = alpha * acc1[j] + om * h[n * 128 + 64 + c];
        Cs[(ng + j) * 128 + c] = o0;
        Cs[(ng + j) * 128 + 64 + c] = o1;
    }
    __syncthreads();
    const int wv = t >> 6, lane = t & 63;
    for (int nl = wv; nl < 16; nl += 4) {
        float v0 = Cs[nl * 128 + lane], v1 = Cs[nl * 128 + 64 + lane];
        float sm = v0 + v1;
#pragma unroll
        for (int off = 32; off >= 1; off >>= 1) sm += __shfl_down(sm, off);
        sm = __shfl(sm, 0);
        float mu = sm * (1.f / 128.f);
        float d0 = v0 - mu, d1 = v1 - mu;
        float sq = d0 * d0 + d1 * d1;
#pragma unroll
        for (int off = 32; off >= 1; off >>= 1) sq += __shfl_down(sq, off);
        sq = __shfl(sq, 0);
        float rs = rsqrtf(sq * (1.f / 128.f) + 1e-5f);
        size_t n = (size_t)(n0 + nl);
        h[n * 128 + lane]      = d0 * rs * lg[lane]      + lb[lane];
        h[n * 128 + 64 + lane] = d1 * rs * lg[64 + lane] + lb[64 + lane];
    }
}

// ---------------- masked mean pool (batch sorted -> binary search) ----------------
__global__ __launch_bounds__(128) void pool_kernel(
    const float* __restrict__ h, const float* __restrict__ x,
    const int* __restrict__ batch, float* __restrict__ pooled)
{
    const int b = blockIdx.x;
    const int c = threadIdx.x;
    int lo = 0, hi = NN;
    while (lo < hi) { int mid = (lo + hi) >> 1; if (batch[mid] < b) lo = mid + 1; else hi = mid; }
    int start = lo;
    lo = 0; hi = NN;
    while (lo < hi) { int mid = (lo + hi) >> 1; if (batch[mid] < b + 1) lo = mid + 1; else hi = mid; }
    int end = lo;
    float sw = 0.f, sn = 0.f, cw = 0.f, cn = 0.f;
    for (int n = start; n < end; ++n) {
        float w = (x[(size_t)n * 5 + 1] > 0.f) ? 1.f : 0.f;
        float hv = h[(size_t)n * 128 + c];
        sw += w * hv; sn += (1.f - w) * hv;
        cw += w; cn += (1.f - w);
    }
    pooled[b * 256 + c]       = (cw > 0.f) ? sw / fmaxf(cw, 1.f) : 0.f;
    pooled[b * 256 + 128 + c] = (cn > 0.f) ? sn / fmaxf(cn, 1.f) : 0.f;
}

// ---------------- MLP head ----------------
__global__ __launch_bounds__(256) void head_kernel(
    const float* __restrict__ pooled, const float* __restrict__ task,
    const float* __restrict__ Wtf, const float* __restrict__ btf,
    const float* __restrict__ Wc1, const float* __restrict__ bc1,
    const float* __restrict__ Wc2, const float* __restrict__ bc2,
    float* __restrict__ out)
{
    __shared__ float in_s[640];
    __shared__ float ge_s[256];
    __shared__ float hc_s[64];
    const int b = blockIdx.x, t = threadIdx.x;
    if (t < 256) in_s[t] = pooled[b * 256 + t];
    for (int i = t; i < 384; i += 256) in_s[256 + i] = task[b * 384 + i];
    __syncthreads();
    float acc = btf[t];
    for (int i = 0; i < 640; ++i) acc += in_s[i] * Wtf[i * 256 + t];
    ge_s[t] = fmaxf(acc, 0.f);
    __syncthreads();
    if (t < 64) {
        float a2 = bc1[t];
        for (int i = 0; i < 256; ++i) a2 += ge_s[i] * Wc1[i * 64 + t];
        hc_s[t] = fmaxf(a2, 0.f);
    }
    __syncthreads();
    if (t < 64) {
        float v = hc_s[t] * Wc2[t];
#pragma unroll
        for (int off = 32; off >= 1; off >>= 1) v += __shfl_down(v, off);
        if (t == 0) out[b] = v + bc2[0];
    }
}

__global__ __launch_bounds__(256) void zero_kernel(float4* __restrict__ p, int count4)
{
    int i = blockIdx.x * 256 + threadIdx.x;
    if (i < count4) p[i] = make_float4(0.f, 0.f, 0.f, 0.f);
}

extern "C" void kernel_launch(void* const* d_in, const int* in_sizes, int n_in,
                              void* d_out, int out_size, void* d_ws, size_t ws_size,
                              hipStream_t stream)
{
    const float* x      = (const float*)d_in[0];
    const int*   ast    = (const int*)d_in[1];
    const int*   batch  = (const int*)d_in[2];
    const int*   ei[3]  = {(const int*)d_in[3], (const int*)d_in[4], (const int*)d_in[5]};
    const float* task   = (const float*)d_in[6];
    const float* emb    = (const float*)d_in[7];
    const float* Win    = (const float*)d_in[8];
    const float* bin_   = (const float*)d_in[9];
    const float* Wkqv   = (const float*)d_in[10];
    const float* bkqv   = (const float*)d_in[11];
    const float* Wk_rel = (const float*)d_in[12];
    const float* Wv_rel = (const float*)d_in[13];
    const float* p_rel  = (const float*)d_in[14];
    const float* Wout   = (const float*)d_in[15];
    const float* bout   = (const float*)d_in[16];
    const float* skip   = (const float*)d_in[17];
    const float* ln_g   = (const float*)d_in[18];
    const float* ln_b   = (const float*)d_in[19];
    const float* Wtf    = (const float*)d_in[20];
    const float* btf    = (const float*)d_in[21];
    const float* Wc1    = (const float*)d_in[22];
    const float* bc1    = (const float*)d_in[23];
    const float* Wc2    = (const float*)d_in[24];
    const float* bc2    = (const float*)d_in[25];
    float* out = (float*)d_out;
    float* ws  = (float*)d_ws;

    float*    h      = ws + OFF_H;
    float*    pA     = ws + OFF_A;              // Pq | Pk in phase A; agg in phase B
    float*    Pq     = pA;
    float*    Pk     = pA + (size_t)NN * 64;
    float*    Pv     = ws + OFF_B;
    unsigned* m_enc  = (unsigned*)(ws + OFF_M);
    float*    z      = ws + OFF_Z;
    float*    sbuf   = ws + OFF_S;
    float*    Wf     = ws + OFF_WF;
    float*    bf     = ws + OFF_BF;
    float*    pooled = ws + OFF_POOL;

    fold_weights<<<14, 256, 0, stream>>>(Wkqv, bkqv, Wk_rel, Wv_rel, Wf, bf);
    input_proj<<<NN / 16, 256, 0, stream>>>(x, ast, emb, Win, bin_, h);

    for (int l = 0; l < 2; ++l) {
        const size_t ls = (size_t)l * 7;   // slots: 0=q, 1..3=k_r, 4..6=v_r
        // zero m + z (contiguous N*8 floats)
        zero_kernel<<<(NN * 8 / 4 + 255) / 256, 256, 0, stream>>>(
            (float4*)(ws + OFF_M), NN * 8 / 4);
        // phase A: scores, one head-pair at a time
        for (int hp = 0; hp < 2; ++hp) {
            gemm_cw<64><<<NN / 32, 256, 0, stream>>>(
                h, Wf + ls * 16384, bf + ls * 128, hp * 64, Pq);
            for (int r = 0; r < 3; ++r) {
                gemm_cw<64><<<NN / 32, 256, 0, stream>>>(
                    h, Wf + (ls + 1 + r) * 16384, bf + (ls + 1 + r) * 128, hp * 64, Pk);
                edge_scores_pair<<<(EE * 2 + 255) / 256, 256, 0, stream>>>(
                    Pq, Pk, ei[r], p_rel + (size_t)(l * 3 + r) * 4 + hp * 2,
                    sbuf + (size_t)r * EE * 4, m_enc, hp);
            }
        }
        expsum<<<(3 * EE * 4 + 255) / 256, 256, 0, stream>>>(
            sbuf, m_enc, z, ei[0], ei[1], ei[2]);
        // phase B: q/kt planes dead -> pA becomes agg
        zero_kernel<<<(NN * 128 / 4 + 255) / 256, 256, 0, stream>>>(
            (float4*)pA, NN * 128 / 4);
        for (int hd = 0; hd < 4; ++hd) {
            for (int r = 0; r < 3; ++r) {
                gemm_cw<32><<<NN / 32, 256, 0, stream>>>(
                    h, Wf + (ls + 4 + r) * 16384, bf + (ls + 4 + r) * 128, hd * 32, Pv);
                edge_agg_head<<<(EE * 32 + 255) / 256, 256, 0, stream>>>(
                    Pv, sbuf + (size_t)r * EE * 4, z, ei[r], pA, hd);
            }
        }
        out_ln<<<NN / 16, 256, 0, stream>>>(
            pA, h, Wout + (size_t)l * 16384, bout + (size_t)l * 128,
            skip + l, ln_g + (size_t)l * 128, ln_b + (size_t)l * 128);
    }

    pool_kernel<<<BB, 128, 0, stream>>>(h, x, batch, pooled);
    head_kernel<<<BB, 256, 0, stream>>>(pooled, task, Wtf, btf, Wc1, bc1, Wc2, bc2, out);
}

// Round 4
// 5553.694 us; speedup vs baseline: 1.0533x; 1.0533x over previous
//
#include <hip/hip_runtime.h>
#include <math.h>

// Problem constants (match reference)
#define NN 200000
#define EE 300000
#define BB 64
#define INV_SQRT_D 0.17677669529663687f

// ---- workspace layout (floats). Total ≈ 62.95M floats = 251.8 MB.
// ws budget is ~256MB-class (252 passed, 329 faulted) -> stay <= 252 MB.
#define OFF_H    ((size_t)0)                   // [N][128] node features
#define OFF_AGG  ((size_t)NN * 128)            // [N][128]: CSR fill (ints) -> Pq|Pk halves -> agg
#define OFF_VT   ((size_t)NN * 256)            // [N][32] vt quarter plane
#define OFF_S    ((size_t)NN * 288)            // [3][E][4] scores -> alpha (in place)
#define OFF_RP   (OFF_S + (size_t)3 * EE * 4)  // rowptr ints [3][N+1], padded to 600016
#define OFF_EIX  (OFF_RP + (size_t)600016)     // eidx ints [3][E]
#define OFF_WF   (OFF_EIX + (size_t)3 * EE)    // 14 x [128][128] folded weights
#define OFF_BF   (OFF_WF + (size_t)14 * 16384)
#define OFF_BS   (OFF_BF + (size_t)14 * 128)   // scan block sums, 3*128 ints
#define OFF_POOL (OFF_BS + (size_t)384)        // psum [B][256] + pcnt [B][2]

#define SCAN_L   (NN + 1)
#define SCAN_E   8
#define SCAN_EPB (256 * SCAN_E)                          // 2048
#define SCAN_NB  ((SCAN_L + SCAN_EPB - 1) / SCAN_EPB)    // 98

__device__ __forceinline__ float gelu_exact(float v) {
    return 0.5f * v * (1.0f + erff(v * 0.70710678118654752f));
}

// ---- fold per-relation head transforms into the projection weights ----
// slot s per layer: 0 = q (plain copy), 1..3 = k@Wk_rel[r], 4..6 = v@Wv_rel[r]
__global__ __launch_bounds__(256) void fold_weights(
    const float* __restrict__ Wkqv, const float* __restrict__ bkqv,
    const float* __restrict__ Wk_rel, const float* __restrict__ Wv_rel,
    float* __restrict__ Wf, float* __restrict__ bf)
{
    __shared__ float Wr[4096];
    const int b = blockIdx.x, t = threadIdx.x;
    const int l = b / 7, s = b % 7;
    const float* Wq = Wkqv + (size_t)l * 49152;   // [128][384]
    if (s == 0) {
        for (int i = t; i < 16384; i += 256) {
            int kk = i >> 7, c = i & 127;
            Wf[(size_t)b * 16384 + i] = Wq[kk * 384 + 128 + c];
        }
        if (t < 128) bf[b * 128 + t] = bkqv[l * 384 + 128 + t];
    } else {
        const int side = (s - 1) / 3, r = (s - 1) % 3;
        const int off = side ? 256 : 0;
        const float* Wrel = (side ? Wv_rel : Wk_rel) + (size_t)(l * 3 + r) * 4096;
        for (int i = t; i < 4096; i += 256) Wr[i] = Wrel[i];
        __syncthreads();
        for (int i = t; i < 16384; i += 256) {
            int kk = i >> 7, c = i & 127, hh = c >> 5, f = c & 31;
            const float* wrow = Wq + kk * 384 + off + hh * 32;
            const float* wr = Wr + hh * 1024 + f;
            float sum = 0.f;
#pragma unroll
            for (int d = 0; d < 32; ++d) sum += wrow[d] * wr[d * 32];
            Wf[(size_t)b * 16384 + i] = sum;
        }
        if (t < 128) {
            int hh = t >> 5, f = t & 31;
            float sum = 0.f;
#pragma unroll
            for (int d = 0; d < 32; ++d)
                sum += bkqv[l * 384 + off + hh * 32 + d] * Wr[hh * 1024 + d * 32 + f];
            bf[b * 128 + t] = sum;
        }
    }
}

// ---------------- input projection: h = [emb[ast], x] @ Win + bin ----------------
__global__ __launch_bounds__(256) void input_proj(
    const float* __restrict__ x, const int* __restrict__ ast,
    const float* __restrict__ emb, const float* __restrict__ Win,
    const float* __restrict__ bin_, float* __restrict__ h)
{
    __shared__ float Ws[69 * 128];
    __shared__ float As[16 * 70];
    const int t = threadIdx.x;
    const int n0 = blockIdx.x * 16;
    for (int i = t; i < 69 * 128; i += 256) Ws[i] = Win[i];
    for (int i = t; i < 16 * 69; i += 256) {
        int nl = i / 69, kk = i - nl * 69;
        int n = n0 + nl;
        float v = (kk < 64) ? emb[ast[n] * 64 + kk] : x[n * 5 + (kk - 64)];
        As[nl * 70 + kk] = v;
    }
    __syncthreads();
    const int c = t & 127;
    const int nh = (t >> 7) * 8;
    float acc[8];
    float bv = bin_[c];
#pragma unroll
    for (int j = 0; j < 8; ++j) acc[j] = bv;
    for (int k = 0; k < 69; ++k) {
        float w = Ws[k * 128 + c];
#pragma unroll
        for (int j = 0; j < 8; ++j) acc[j] += As[(nh + j) * 70 + k] * w;
    }
#pragma unroll
    for (int j = 0; j < 8; ++j) h[(size_t)(n0 + nh + j) * 128 + c] = acc[j];
}

// ---- CSR build: histogram -> scan -> scatter ----
__global__ __launch_bounds__(256) void csr_hist(
    const int* __restrict__ ei0, const int* __restrict__ ei1, const int* __restrict__ ei2,
    int* __restrict__ rp)
{
    int idx = blockIdx.x * 256 + threadIdx.x;
    if (idx >= 3 * EE) return;
    int r = idx / EE, e = idx - r * EE;
    const int* ei = (r == 0) ? ei0 : ((r == 1) ? ei1 : ei2);
    atomicAdd(&rp[r * SCAN_L + ei[EE + e] + 1], 1);
}

__global__ __launch_bounds__(256) void scan1(int* __restrict__ rp, int* __restrict__ bs)
{
    __shared__ int ts[256];
    const int r = blockIdx.y;
    int* a = rp + (size_t)r * SCAN_L;
    const int base = blockIdx.x * SCAN_EPB + threadIdx.x * SCAN_E;
    int v[SCAN_E];
    int tot = 0;
#pragma unroll
    for (int j = 0; j < SCAN_E; ++j) {
        int idx = base + j;
        v[j] = (idx < SCAN_L) ? a[idx] : 0;
        tot += v[j];
    }
    ts[threadIdx.x] = tot;
    __syncthreads();
    for (int st = 1; st < 256; st <<= 1) {
        int add = (threadIdx.x >= st) ? ts[threadIdx.x - st] : 0;
        __syncthreads();
        ts[threadIdx.x] += add;
        __syncthreads();
    }
    int run = ts[threadIdx.x] - tot;   // exclusive prefix of this thread
#pragma unroll
    for (int j = 0; j < SCAN_E; ++j) {
        run += v[j];
        int idx = base + j;
        if (idx < SCAN_L) a[idx] = run;   // inclusive scan in place
    }
    if (threadIdx.x == 255) bs[r * 128 + blockIdx.x] = ts[255];
}

__global__ __launch_bounds__(128) void scan2(int* __restrict__ bs)
{
    __shared__ int ts[128];
    const int r = blockIdx.x, t = threadIdx.x;
    int v = (t < SCAN_NB) ? bs[r * 128 + t] : 0;
    ts[t] = v;
    __syncthreads();
    for (int st = 1; st < 128; st <<= 1) {
        int add = (t >= st) ? ts[t - st] : 0;
        __syncthreads();
        ts[t] += add;
        __syncthreads();
    }
    bs[r * 128 + t] = ts[t];   // inclusive block sums
}

__global__ __launch_bounds__(256) void scan3(int* __restrict__ rp, const int* __restrict__ bs)
{
    const int r = blockIdx.y;
    if (blockIdx.x == 0) return;
    const int off = bs[r * 128 + blockIdx.x - 1];
    const int base = blockIdx.x * SCAN_EPB + threadIdx.x * SCAN_E;
    int* a = rp + (size_t)r * SCAN_L;
#pragma unroll
    for (int j = 0; j < SCAN_E; ++j) {
        int idx = base + j;
        if (idx < SCAN_L) a[idx] += off;
    }
}

__global__ __launch_bounds__(256) void csr_scatter(
    const int* __restrict__ ei0, const int* __restrict__ ei1, const int* __restrict__ ei2,
    const int* __restrict__ rp, int* __restrict__ fill, int* __restrict__ eidx)
{
    int idx = blockIdx.x * 256 + threadIdx.x;
    if (idx >= 3 * EE) return;
    int r = idx / EE, e = idx - r * EE;
    const int* ei = (r == 0) ? ei0 : ((r == 1) ? ei1 : ei2);
    int dst = ei[EE + e];
    int pos = rp[r * SCAN_L + dst] + atomicAdd(&fill[r * NN + dst], 1);
    eidx[r * EE + pos] = e;
}

// ---- column-sliced GEMM: out[n][0:CW] = in[n][0:128] @ W[:, c0:c0+CW] + bias ----
template<int CW>
__global__ __launch_bounds__(256) void gemm_cw(
    const float* __restrict__ in, const float* __restrict__ W,
    const float* __restrict__ bias, int c0, float* __restrict__ outp)
{
    constexpr int NG = 256 / CW;
    constexpr int NR = 32 / NG;
    __shared__ float As[32 * 128];
    __shared__ float Ws[128 * CW];
    const int t = threadIdx.x;
    const int n0 = blockIdx.x * 32;
    for (int i = t; i < 32 * 32; i += 256) {
        int nl = i >> 5, k4 = i & 31;
        ((float4*)As)[nl * 32 + k4] = *(const float4*)(in + (size_t)(n0 + nl) * 128 + k4 * 4);
    }
    constexpr int C4 = CW / 4;
    for (int i = t; i < 128 * C4; i += 256) {
        int k = i / C4, c4 = i % C4;
        ((float4*)Ws)[i] = *(const float4*)(W + (size_t)k * 128 + c0 + c4 * 4);
    }
    __syncthreads();
    const int c = t % CW;
    const int ng = (t / CW) * NR;
    float acc[NR];
    float bv = bias[c0 + c];
#pragma unroll
    for (int j = 0; j < NR; ++j) acc[j] = bv;
    for (int k = 0; k < 128; ++k) {
        float w = Ws[k * CW + c];
#pragma unroll
        for (int j = 0; j < NR; ++j) acc[j] += As[(ng + j) * 128 + k] * w;
    }
#pragma unroll
    for (int j = 0; j < NR; ++j)
        outp[(size_t)(n0 + ng + j) * CW + c] = acc[j];
}

// ---- edge scores for head-pair hp (heads 2hp, 2hp+1); no atomics ----
__global__ __launch_bounds__(256) void edge_scores_pair(
    const float* __restrict__ q64, const float* __restrict__ k64,
    const int* __restrict__ ei, const float* __restrict__ p2,
    float* __restrict__ s, int r, int hp)
{
    int idx = blockIdx.x * 256 + threadIdx.x;
    if (idx >= EE * 2) return;
    int e = idx >> 1, hh = idx & 1;
    int src = ei[e], dst = ei[EE + e];
    const float4* qp = (const float4*)(q64 + (size_t)dst * 64 + hh * 32);
    const float4* kp = (const float4*)(k64 + (size_t)src * 64 + hh * 32);
    float sum = 0.f;
#pragma unroll
    for (int i = 0; i < 8; ++i) {
        float4 a = qp[i], b = kp[i];
        sum += a.x * b.x + a.y * b.y + a.z * b.z + a.w * b.w;
    }
    s[((size_t)r * EE + e) * 4 + hp * 2 + hh] = sum * p2[hh] * INV_SQRT_D;
}

// ---- CSR segment softmax (one wave per dst, all 3 relations x 4 heads) ----
__global__ __launch_bounds__(256) void csr_softmax(
    float* __restrict__ s, const int* __restrict__ rp, const int* __restrict__ eidx)
{
    const int dst = blockIdx.x * 4 + (threadIdx.x >> 6);
    const int lane = threadIdx.x & 63;
    const int sub = lane >> 2, hh = lane & 3;
    int beg[3], end[3];
#pragma unroll
    for (int r = 0; r < 3; ++r) {
        beg[r] = rp[r * SCAN_L + dst];
        end[r] = rp[r * SCAN_L + dst + 1];
    }
    float m = -INFINITY;
#pragma unroll
    for (int r = 0; r < 3; ++r)
        for (int p = beg[r] + sub; p < end[r]; p += 16) {
            int e = eidx[r * EE + p];
            m = fmaxf(m, s[((size_t)r * EE + e) * 4 + hh]);
        }
#pragma unroll
    for (int st = 4; st < 64; st <<= 1) m = fmaxf(m, __shfl_xor(m, st));
    float zz = 0.f;
#pragma unroll
    for (int r = 0; r < 3; ++r)
        for (int p = beg[r] + sub; p < end[r]; p += 16) {
            int e = eidx[r * EE + p];
            size_t off = ((size_t)r * EE + e) * 4 + hh;
            float ex = expf(s[off] - m);
            s[off] = ex;
            zz += ex;
        }
#pragma unroll
    for (int st = 4; st < 64; st <<= 1) zz += __shfl_xor(zz, st);
    float inv = 1.f / (zz + 1e-16f);
#pragma unroll
    for (int r = 0; r < 3; ++r)
        for (int p = beg[r] + sub; p < end[r]; p += 16) {
            int e = eidx[r * EE + p];
            s[((size_t)r * EE + e) * 4 + hh] *= inv;
        }
}

// ---- CSR aggregation: half-wave (32 lanes) per dst; no atomics ----
__global__ __launch_bounds__(256) void csr_agg(
    const float* __restrict__ vt, const float* __restrict__ s,
    const int* __restrict__ rp, const int* __restrict__ eidx,
    const int* __restrict__ ei_src, float* __restrict__ agg, int r, int hd)
{
    const int dst = blockIdx.x * 8 + (threadIdx.x >> 5);
    const int c = threadIdx.x & 31;
    const int beg = rp[r * SCAN_L + dst];
    const int end = rp[r * SCAN_L + dst + 1];
    if (beg == end) return;
    float acc = 0.f;
    for (int p = beg; p < end; ++p) {
        int e = eidx[r * EE + p];
        int src = ei_src[e];
        float a = s[((size_t)r * EE + e) * 4 + hd];
        acc += a * vt[(size_t)src * 32 + c];
    }
    size_t off = (size_t)dst * 128 + hd * 32 + c;
    agg[off] += acc;
}

// ---------------- out-proj + gelu + skip + LayerNorm (in-place h update) ----------------
__global__ __launch_bounds__(256) void out_ln(
    const float* __restrict__ agg, float* __restrict__ h,
    const float* __restrict__ Wout, const float* __restrict__ bout,
    const float* __restrict__ skipp, const float* __restrict__ lg,
    const float* __restrict__ lb)
{
    __shared__ float As[16 * 128];
    __shared__ float Ws[64 * 128];
    __shared__ float Cs[16 * 128];
    const int t = threadIdx.x;
    const int n0 = blockIdx.x * 16;
    for (int i = t; i < 16 * 32; i += 256) {
        int nl = i >> 5, k4 = i & 31;
        float4 v = *(const float4*)(agg + (size_t)(n0 + nl) * 128 + k4 * 4);
        v.x = gelu_exact(v.x); v.y = gelu_exact(v.y);
        v.z = gelu_exact(v.z); v.w = gelu_exact(v.w);
        ((float4*)As)[nl * 32 + k4] = v;
    }
    const int c = t & 63;
    const int ng = (t >> 6) * 4;
    float acc0[4], acc1[4];
    float b0 = bout[c], b1 = bout[64 + c];
#pragma unroll
    for (int j = 0; j < 4; ++j) { acc0[j] = b0; acc1[j] = b1; }
    for (int kc = 0; kc < 2; ++kc) {
        __syncthreads();
        for (int i = t; i < 64 * 32; i += 256) {
            int k = i >> 5, c4 = i & 31;
            ((float4*)Ws)[i] = *(const float4*)(Wout + (size_t)(kc * 64 + k) * 128 + c4 * 4);
        }
        __syncthreads();
        const float* Ab = As + kc * 64;
        for (int k = 0; k < 64; ++k) {
            float w0 = Ws[k * 128 + c];
            float w1 = Ws[k * 128 + 64 + c];
#pragma unroll
            for (int j = 0; j < 4; ++j) {
                float a = Ab[(ng + j) * 128 + k];
                acc0[j] += a * w0;
                acc1[j] += a * w1;
            }
        }
    }
    float alpha = 1.f / (1.f + expf(-skipp[0]));
    float om = 1.f - alpha;
#pragma unroll
    for (int j = 0; j < 4; ++j) {
        size_t n = (size_t)(n0 + ng + j);
        float o0 = alpha * acc0[j] + om * h[n * 128 + c];
        float o1 = alpha * acc1[j] + om * h[n * 128 + 64 + c];
        Cs[(ng + j) * 128 + c] = o0;
        Cs[(ng + j) * 128 + 64 + c] = o1;
    }
    __syncthreads();
    const int wv = t >> 6, lane = t & 63;
    for (int nl = wv; nl < 16; nl += 4) {
        float v0 = Cs[nl * 128 + lane], v1 = Cs[nl * 128 + 64 + lane];
        float sm = v0 + v1;
#pragma unroll
        for (int off = 32; off >= 1; off >>= 1) sm += __shfl_down(sm, off);
        sm = __shfl(sm, 0);
        float mu = sm * (1.f / 128.f);
        float d0 = v0 - mu, d1 = v1 - mu;
        float sq = d0 * d0 + d1 * d1;
#pragma unroll
        for (int off = 32; off >= 1; off >>= 1) sq += __shfl_down(sq, off);
        sq = __shfl(sq, 0);
        float rs = rsqrtf(sq * (1.f / 128.f) + 1e-5f);
        size_t n = (size_t)(n0 + nl);
        h[n * 128 + lane]      = d0 * rs * lg[lane]      + lb[lane];
        h[n * 128 + 64 + lane] = d1 * rs * lg[64 + lane] + lb[64 + lane];
    }
}

// ---- parallel masked mean-pool partials (batch sorted -> run-flush) ----
__global__ __launch_bounds__(256) void pool_partial(
    const float* __restrict__ h, const float* __restrict__ x,
    const int* __restrict__ batch, float* __restrict__ psum, float* __restrict__ pcnt)
{
    const int c = threadIdx.x & 127;
    const int n0 = blockIdx.x * 64 + (threadIdx.x >> 7) * 32;
    int g = batch[n0];
    float sw = 0.f, sn = 0.f, cw = 0.f, cn = 0.f;
    for (int i = 0; i < 32; ++i) {
        int n = n0 + i;
        int gn = batch[n];
        if (gn != g) {
            atomicAdd(&psum[g * 256 + c], sw);
            atomicAdd(&psum[g * 256 + 128 + c], sn);
            if (c == 0) { atomicAdd(&pcnt[g * 2], cw); atomicAdd(&pcnt[g * 2 + 1], cn); }
            sw = sn = cw = cn = 0.f;
            g = gn;
        }
        float w = (x[(size_t)n * 5 + 1] > 0.f) ? 1.f : 0.f;
        float hv = h[(size_t)n * 128 + c];
        sw += w * hv; sn += (1.f - w) * hv;
        cw += w; cn += 1.f - w;
    }
    atomicAdd(&psum[g * 256 + c], sw);
    atomicAdd(&psum[g * 256 + 128 + c], sn);
    if (c == 0) { atomicAdd(&pcnt[g * 2], cw); atomicAdd(&pcnt[g * 2 + 1], cn); }
}

// ---------------- MLP head (pool finalize fused into the load) ----------------
__global__ __launch_bounds__(256) void head_kernel(
    const float* __restrict__ psum, const float* __restrict__ pcnt,
    const float* __restrict__ task,
    const float* __restrict__ Wtf, const float* __restrict__ btf,
    const float* __restrict__ Wc1, const float* __restrict__ bc1,
    const float* __restrict__ Wc2, const float* __restrict__ bc2,
    float* __restrict__ out)
{
    __shared__ float in_s[640];
    __shared__ float ge_s[256];
    __shared__ float hc_s[64];
    const int b = blockIdx.x, t = threadIdx.x;
    if (t < 256) {
        float cnt = pcnt[b * 2 + (t >> 7)];
        float sv = psum[b * 256 + t];
        in_s[t] = (cnt > 0.f) ? sv / fmaxf(cnt, 1.f) : 0.f;
    }
    for (int i = t; i < 384; i += 256) in_s[256 + i] = task[b * 384 + i];
    __syncthreads();
    float acc = btf[t];
    for (int i = 0; i < 640; ++i) acc += in_s[i] * Wtf[i * 256 + t];
    ge_s[t] = fmaxf(acc, 0.f);
    __syncthreads();
    if (t < 64) {
        float a2 = bc1[t];
        for (int i = 0; i < 256; ++i) a2 += ge_s[i] * Wc1[i * 64 + t];
        hc_s[t] = fmaxf(a2, 0.f);
    }
    __syncthreads();
    if (t < 64) {
        float v = hc_s[t] * Wc2[t];
#pragma unroll
        for (int off = 32; off >= 1; off >>= 1) v += __shfl_down(v, off);
        if (t == 0) out[b] = v + bc2[0];
    }
}

__global__ __launch_bounds__(256) void zero_kernel(float4* __restrict__ p, int count4)
{
    int i = blockIdx.x * 256 + threadIdx.x;
    if (i < count4) p[i] = make_float4(0.f, 0.f, 0.f, 0.f);
}

extern "C" void kernel_launch(void* const* d_in, const int* in_sizes, int n_in,
                              void* d_out, int out_size, void* d_ws, size_t ws_size,
                              hipStream_t stream)
{
    const float* x      = (const float*)d_in[0];
    const int*   ast    = (const int*)d_in[1];
    const int*   batch  = (const int*)d_in[2];
    const int*   ei[3]  = {(const int*)d_in[3], (const int*)d_in[4], (const int*)d_in[5]};
    const float* task   = (const float*)d_in[6];
    const float* emb    = (const float*)d_in[7];
    const float* Win    = (const float*)d_in[8];
    const float* bin_   = (const float*)d_in[9];
    const float* Wkqv   = (const float*)d_in[10];
    const float* bkqv   = (const float*)d_in[11];
    const float* Wk_rel = (const float*)d_in[12];
    const float* Wv_rel = (const float*)d_in[13];
    const float* p_rel  = (const float*)d_in[14];
    const float* Wout   = (const float*)d_in[15];
    const float* bout   = (const float*)d_in[16];
    const float* skip   = (const float*)d_in[17];
    const float* ln_g   = (const float*)d_in[18];
    const float* ln_b   = (const float*)d_in[19];
    const float* Wtf    = (const float*)d_in[20];
    const float* btf    = (const float*)d_in[21];
    const float* Wc1    = (const float*)d_in[22];
    const float* bc1    = (const float*)d_in[23];
    const float* Wc2    = (const float*)d_in[24];
    const float* bc2    = (const float*)d_in[25];
    float* out = (float*)d_out;
    float* ws  = (float*)d_ws;

    float* h    = ws + OFF_H;
    float* pA   = ws + OFF_AGG;              // fill (build) -> Pq|Pk (phase A) -> agg (phase B)
    float* Pq   = pA;
    float* Pk   = pA + (size_t)NN * 64;
    float* Pv   = ws + OFF_VT;
    float* sbuf = ws + OFF_S;
    int*   rp   = (int*)(ws + OFF_RP);
    int*   eidx = (int*)(ws + OFF_EIX);
    int*   fill = (int*)pA;
    float* Wf   = ws + OFF_WF;
    float* bf   = ws + OFF_BF;
    int*   bs   = (int*)(ws + OFF_BS);
    float* psum = ws + OFF_POOL;
    float* pcnt = psum + (size_t)BB * 256;

    // ---- one-time per call: fold weights, input proj, CSR build ----
    fold_weights<<<14, 256, 0, stream>>>(Wkqv, bkqv, Wk_rel, Wv_rel, Wf, bf);
    input_proj<<<NN / 16, 256, 0, stream>>>(x, ast, emb, Win, bin_, h);

    zero_kernel<<<(600016 / 4 + 255) / 256, 256, 0, stream>>>((float4*)rp, 600016 / 4);
    zero_kernel<<<(600000 / 4 + 255) / 256, 256, 0, stream>>>((float4*)fill, 600000 / 4);
    csr_hist<<<(3 * EE + 255) / 256, 256, 0, stream>>>(ei[0], ei[1], ei[2], rp);
    scan1<<<dim3(SCAN_NB, 3), 256, 0, stream>>>(rp, bs);
    scan2<<<3, 128, 0, stream>>>(bs);
    scan3<<<dim3(SCAN_NB, 3), 256, 0, stream>>>(rp, bs);
    csr_scatter<<<(3 * EE + 255) / 256, 256, 0, stream>>>(ei[0], ei[1], ei[2], rp, fill, eidx);

    for (int l = 0; l < 2; ++l) {
        const size_t ls = (size_t)l * 7;   // slots: 0=q, 1..3=k_r, 4..6=v_r
        // phase A: scores (edge-parallel, no atomics)
        for (int hp = 0; hp < 2; ++hp) {
            gemm_cw<64><<<NN / 32, 256, 0, stream>>>(
                h, Wf + ls * 16384, bf + ls * 128, hp * 64, Pq);
            for (int r = 0; r < 3; ++r) {
                gemm_cw<64><<<NN / 32, 256, 0, stream>>>(
                    h, Wf + (ls + 1 + r) * 16384, bf + (ls + 1 + r) * 128, hp * 64, Pk);
                edge_scores_pair<<<(EE * 2 + 255) / 256, 256, 0, stream>>>(
                    Pq, Pk, ei[r], p_rel + (size_t)(l * 3 + r) * 4 + hp * 2, sbuf, r, hp);
            }
        }
        csr_softmax<<<NN / 4, 256, 0, stream>>>(sbuf, rp, eidx);
        // phase B: Pq/Pk dead -> pA becomes agg
        zero_kernel<<<(NN * 128 / 4 + 255) / 256, 256, 0, stream>>>(
            (float4*)pA, NN * 128 / 4);
        for (int hd = 0; hd < 4; ++hd) {
            for (int r = 0; r < 3; ++r) {
                gemm_cw<32><<<NN / 32, 256, 0, stream>>>(
                    h, Wf + (ls + 4 + r) * 16384, bf + (ls + 4 + r) * 128, hd * 32, Pv);
                csr_agg<<<NN / 8, 256, 0, stream>>>(
                    Pv, sbuf, rp, eidx, ei[r], pA, r, hd);
            }
        }
        out_ln<<<NN / 16, 256, 0, stream>>>(
            pA, h, Wout + (size_t)l * 16384, bout + (size_t)l * 128,
            skip + l, ln_g + (size_t)l * 128, ln_b + (size_t)l * 128);
    }

    zero_kernel<<<(16512 / 4 + 255) / 256, 256, 0, stream>>>((float4*)psum, 16512 / 4);
    pool_partial<<<NN / 64, 256, 0, stream>>>(h, x, batch, psum, pcnt);
    head_kernel<<<BB, 256, 0, stream>>>(psum, pcnt, task, Wtf, btf, Wc1, bc1, Wc2, bc2, out);
}